// Round 20
// baseline (188.922 us; speedup 1.0000x reference)
//
#include <hip/hip_runtime.h>

typedef unsigned short u16;
typedef unsigned int u32;
typedef __attribute__((ext_vector_type(4))) float f32x4;
typedef __attribute__((ext_vector_type(16))) float f32x16;
typedef __attribute__((ext_vector_type(8))) __bf16 bf16x8;
typedef __attribute__((ext_vector_type(4))) _Float16 f16x4;
typedef __attribute__((ext_vector_type(8))) _Float16 f16x8;
typedef __attribute__((ext_vector_type(4))) u16 u16x4;
typedef __attribute__((ext_vector_type(4))) u32 u32x4;
typedef __attribute__((ext_vector_type(2))) u32 u32x2;

#define D_ 1024
#define S_ 2048
#define B_ 4
#define H_ 16
#define HD_ 64
#define M_ 8192
#define LDP 72
#define QSCALE 0.18033688011112042591f /* 0.125 * log2(e) */

__device__ __forceinline__ u16 f2bf(float f) {
  u32 u = __float_as_uint(f);
  u += 0x7fffu + ((u >> 16) & 1u);
  return (u16)(u >> 16);
}

__device__ __forceinline__ float max3f(float a, float b, float c) {
  return fmaxf(fmaxf(a, b), c);  // clang fuses to v_max3_f32
}

// async 16B global->LDS DMA; LDS dest = wave-uniform base + lane*16 (linear!)
__device__ __forceinline__ void gload_lds16(const void* g, void* l) {
  __builtin_amdgcn_global_load_lds((const __attribute__((address_space(1))) void*)g,
                                   (__attribute__((address_space(3))) void*)l, 16, 0, 0);
}

// ---------------- fused prep: cast x (fp32->bf16) + transpose+cast weights ----------------
__global__ __launch_bounds__(256) void prep_kernel(const float* __restrict__ x, u16* __restrict__ xb,
                                                   const float* __restrict__ Wq, const float* __restrict__ Wk,
                                                   const float* __restrict__ Wv, const float* __restrict__ Wo,
                                                   u16* __restrict__ Wqt, u16* __restrict__ Wkt,
                                                   u16* __restrict__ Wvt, u16* __restrict__ Wot) {
  __shared__ float lds[64][65];
  int lin = blockIdx.x;
  if (lin < 8192) {
    int i = (lin * 256 + threadIdx.x) * 4;
    f32x4 v = *(const f32x4*)(x + i);
    u16x4 o = {f2bf(v[0]), f2bf(v[1]), f2bf(v[2]), f2bf(v[3])};
    *(u16x4*)(xb + i) = o;
    return;
  }
  int pos = lin - 8192;
  int z = pos >> 8, rem = pos & 255;
  const float* W = z == 0 ? Wq : z == 1 ? Wk : z == 2 ? Wv : Wo;
  u16* Wt       = z == 0 ? Wqt : z == 1 ? Wkt : z == 2 ? Wvt : Wot;
  int k0 = (rem >> 4) * 64, n0 = (rem & 15) * 64;
  int tr = threadIdx.x >> 6, tc = threadIdx.x & 63;
#pragma unroll
  for (int i = 0; i < 16; ++i)
    lds[tr + i * 4][tc] = W[(size_t)(k0 + tr + i * 4) * D_ + n0 + tc];
  __syncthreads();
#pragma unroll
  for (int i = 0; i < 16; ++i)
    Wt[(size_t)(n0 + tr + i * 4) * D_ + k0 + tc] = f2bf(lds[tc][tr + i * 4]);
}

// ---------------- shared 128x128 GEMM mainloop (global_load_lds staging, XOR swizzle) ----------------
__device__ __forceinline__ void gemm_main(const u16* __restrict__ A, const u16* __restrict__ Bt,
                                          u16* As, u16* Bs, int row0, int col0, f32x4 acc[4][4]) {
  const int tid = threadIdx.x;
  const int lane = tid & 63, wave = tid >> 6;
  const int wr = wave >> 1, wc = wave & 1;
  const int l15 = lane & 15, lg = lane >> 4;
  const int sr8 = lane >> 3;        // row within this wave's 8-row chunk (= r&7)
  const int scx = (lane & 7) ^ sr8; // pre-swizzled source k-chunk
#pragma unroll 1
  for (int k0 = 0; k0 < D_; k0 += 64) {
    // issue async stages: 4 wave-chunks of 8 rows for A and B each
#pragma unroll
    for (int it = 0; it < 4; ++it) {
      int rbase = (it * 4 + wave) * 8;
      int r = rbase + sr8;
      gload_lds16(A + (size_t)(row0 + r) * D_ + k0 + scx * 8, As + rbase * 64);
      gload_lds16(Bt + (size_t)(col0 + r) * D_ + k0 + scx * 8, Bs + rbase * 64);
    }
    __syncthreads();  // drains vmcnt -> DMA writes visible; syncs waves
#pragma unroll
    for (int kk = 0; kk < 64; kk += 32) {
      const int cb = kk >> 3;  // 0 or 4
      bf16x8 af[4], bf[4];
#pragma unroll
      for (int m = 0; m < 4; ++m) {
        int row = wr * 64 + m * 16 + l15;
        af[m] = *(const bf16x8*)(As + row * 64 + (((cb + lg) ^ (l15 & 7)) << 3));
      }
#pragma unroll
      for (int n = 0; n < 4; ++n) {
        int row = wc * 64 + n * 16 + l15;
        bf[n] = *(const bf16x8*)(Bs + row * 64 + (((cb + lg) ^ (l15 & 7)) << 3));
      }
#pragma unroll
      for (int m = 0; m < 4; ++m)
#pragma unroll
        for (int n = 0; n < 4; ++n)
          acc[m][n] = __builtin_amdgcn_mfma_f32_16x16x32_bf16(af[m], bf[n], acc[m][n], 0, 0, 0);
    }
    __syncthreads();  // readers done before next iteration's DMA writes
  }
}

// ---------------- QKV projection GEMM (1D grid, XCD-clustered swizzle) ----------------
__global__ __launch_bounds__(256) void qkv_gemm_kernel(const u16* __restrict__ xb,
                                                       const u16* __restrict__ Wqt, const u16* __restrict__ Wkt,
                                                       const u16* __restrict__ Wvt,
                                                       u16* __restrict__ Qb, u16* __restrict__ Kb,
                                                       _Float16* __restrict__ Vt) {
  __shared__ u16 As[128 * 64];
  __shared__ u16 Bs[128 * 64];
  int lin = blockIdx.x;
  int xcd = lin & 7, pos = lin >> 3;      // pos in [0,192)
  int mode = pos / 64;                    // z outer
  int rem = pos & 63;
  int by = xcd * 8 + (rem >> 3);          // row-panel
  int bx = rem & 7;                       // col-tile
  const u16* Bt = mode == 0 ? Wqt : mode == 1 ? Wkt : Wvt;
  f32x4 acc[4][4] = {};
  int row0 = by * 128, col0 = bx * 128;
  gemm_main(xb, Bt, As, Bs, row0, col0, acc);
  int lane = threadIdx.x & 63, wave = threadIdx.x >> 6;
  int wr = wave >> 1, wc = wave & 1, l15 = lane & 15, lg = lane >> 4;
  int rbase = row0 + wr * 64 + lg * 4, cbase = col0 + wc * 64 + l15;
  if (mode == 2) {
#pragma unroll
    for (int m = 0; m < 4; ++m) {
      int row = rbase + m * 16;
      int b = row >> 11, s = row & (S_ - 1);
#pragma unroll
      for (int n = 0; n < 4; ++n) {
        int col = cbase + n * 16;
        int h = col >> 6, hd = col & 63;
        f16x4 vv = {(_Float16)acc[m][n][0], (_Float16)acc[m][n][1],
                    (_Float16)acc[m][n][2], (_Float16)acc[m][n][3]};
        *(f16x4*)(Vt + ((size_t)((b << 4) + h) * HD_ + hd) * S_ + s) = vv;
      }
    }
  } else {
    u16* dst = mode == 0 ? Qb : Kb;
    float scl = mode == 0 ? QSCALE : 1.0f;
#pragma unroll
    for (int m = 0; m < 4; ++m)
#pragma unroll
      for (int n = 0; n < 4; ++n) {
        int col = cbase + n * 16;
#pragma unroll
        for (int r = 0; r < 4; ++r) {
          int row = rbase + m * 16 + r;
          dst[(size_t)row * D_ + col] = f2bf(acc[m][n][r] * scl);
        }
      }
  }
}

// ---------------- fused causal flash attention, v16: 32x32 MFMA, 4-wave blocks share staging ----------------
// Block = 4 waves / 256 threads / 128 q rows; 1024 blocks (qblk128 x bh), LPT, XCD clustering,
// single-buffer 18KB LDS shared by all 4 waves -> staging traffic & barriers per unit compute halve.
// Wave w owns rows wq0 = qblk*128 + w*32; per-wave diagonal tile tdiag = wq0>>6 (waves 0-1 finish
// one tile before waves 2-3; inactive waves still stage + barrier). v15 math otherwise unchanged.
__global__ __launch_bounds__(256) void attn_kernel(const u16* __restrict__ Qb, const u16* __restrict__ Kb,
                                                   const _Float16* __restrict__ Vt, u16* __restrict__ attnb) {
  __shared__ u16 Ks[64][LDP];       // [kv][hd]
  __shared__ _Float16 Vs[64][LDP];  // [hd][kv]
  const int tid = threadIdx.x;
  const int wave = tid >> 6, lane = tid & 63;
  const int l31 = lane & 31, hi = lane >> 5;
  const int lin = blockIdx.x;
  const int xcd = lin & 7, slot = lin >> 3;   // slot 0..127
  const int qblk = 15 - (slot >> 3);          // 128-row q block, LPT: biggest first
  const int bh = (slot & 7) * 8 + xcd;        // bh&7 == xcd
  const int b = bh >> 4, h = bh & 15;
  const int ntiles = 2 * qblk + 2;
  const int wq0 = qblk * 128 + wave * 32;     // wave's rows [wq0, wq0+32)
  const int qg = wq0 + l31;                   // this lane's q row
  const int tdiag = wq0 >> 6;                 // wave's diagonal tile (wq0%64 in {0,32})

  // staging: thread covers K/V row (tid>>2), chunks (tid&3)*16 and +8 (elems)
  const int srow = tid >> 2;
  const int sc = (tid & 3) * 16;
  const u16* Kp = Kb + (size_t)(b * S_ + srow) * D_ + h * HD_ + sc;
  const _Float16* Vp = Vt + ((size_t)bh * HD_ + srow) * S_ + sc;

  // Q B-fragments per 16-wide d-step
  const u16* Qrow = Qb + (size_t)(b * S_ + qg) * D_ + h * HD_;
  bf16x8 qf[4];
#pragma unroll
  for (int ds = 0; ds < 4; ++ds)
    qf[ds] = *(const bf16x8*)(Qrow + ds * 16 + hi * 8);

  float m = -1e30f;
  f32x16 oL = {}, oH = {};   // o^T rows hd 0..31 / 32..63, col q = l31
  f32x16 osum = {};          // ones-MFMA row-sum
  const f16x8 ones8 = {(_Float16)1.f, (_Float16)1.f, (_Float16)1.f, (_Float16)1.f,
                       (_Float16)1.f, (_Float16)1.f, (_Float16)1.f, (_Float16)1.f};
  u32x4 kst0, kst1, vst0, vst1;

  // tile body (domask wave-uniform)
  auto tile_body = [&](int kvb, bool domask) {
    f32x16 sA = {}, sB = {};
    __builtin_amdgcn_s_setprio(1);
#pragma unroll
    for (int ds = 0; ds < 4; ++ds) {
      bf16x8 k0 = *(const bf16x8*)(&Ks[l31][ds * 16 + hi * 8]);
      bf16x8 k1 = *(const bf16x8*)(&Ks[32 + l31][ds * 16 + hi * 8]);
      sA = __builtin_amdgcn_mfma_f32_32x32x16_bf16(k0, qf[ds], sA, 0, 0, 0);
      sB = __builtin_amdgcn_mfma_f32_32x32x16_bf16(k1, qf[ds], sB, 0, 0, 0);
    }
    __builtin_amdgcn_s_setprio(0);
    if (domask) {
#pragma unroll
      for (int r = 0; r < 16; ++r) {
        int off = (r & 3) + 8 * (r >> 2) + 4 * hi;
        if (kvb + off > qg) sA[r] = -1e30f;
        if (kvb + 32 + off > qg) sB[r] = -1e30f;
      }
    }
    float mx[16];
#pragma unroll
    for (int r = 0; r < 16; ++r) mx[r] = fmaxf(sA[r], sB[r]);
    float y0 = max3f(mx[0], mx[1], mx[2]);
    float y1 = max3f(mx[3], mx[4], mx[5]);
    float y2 = max3f(mx[6], mx[7], mx[8]);
    float y3 = max3f(mx[9], mx[10], mx[11]);
    float y4 = max3f(mx[12], mx[13], mx[14]);
    float tmax = fmaxf(max3f(y0, y1, y2), max3f(y3, y4, mx[15]));
    tmax = fmaxf(tmax, __shfl_xor(tmax, 32));
    if (!__all(tmax - m <= 8.f)) {  // defer-max (T13)
      float nm = fmaxf(m, tmax);
      float alpha = exp2f(m - nm);
      m = nm;
      osum *= alpha;
      oL *= alpha;
      oH *= alpha;
    }
#pragma unroll
    for (int r = 0; r < 16; ++r) {
      sA[r] = exp2f(sA[r] - m);
      sB[r] = exp2f(sB[r] - m);
    }
    u32 uA[8], uB[8], vA[8], vB[8];
#pragma unroll
    for (int k = 0; k < 8; ++k) {
      uA[k] = __builtin_bit_cast(u32, __builtin_amdgcn_cvt_pkrtz(sA[2 * k], sA[2 * k + 1]));
      uB[k] = __builtin_bit_cast(u32, __builtin_amdgcn_cvt_pkrtz(sB[2 * k], sB[2 * k + 1]));
    }
#pragma unroll
    for (int k = 0; k < 8; ++k) {
      vA[k] = __shfl_xor(uA[k], 32);
      vB[k] = __shfl_xor(uB[k], 32);
    }
    __builtin_amdgcn_s_setprio(1);
#pragma unroll
    for (int ks = 0; ks < 4; ++ks) {
      const u32* U = (ks >> 1) ? uB : uA;
      const u32* Vw = (ks >> 1) ? vB : vA;
      const int b4 = (ks & 1) * 4;
      u32 w0 = hi ? Vw[b4 + 2] : U[b4 + 0];
      u32 w1 = hi ? Vw[b4 + 3] : U[b4 + 1];
      u32 w2 = hi ? U[b4 + 2] : Vw[b4 + 0];
      u32 w3 = hi ? U[b4 + 3] : Vw[b4 + 1];
      f16x8 pa = __builtin_bit_cast(f16x8, (u32x4){w0, w1, w2, w3});
      f16x8 v0 = *(const f16x8*)(&Vs[l31][ks * 16 + hi * 8]);
      f16x8 v1 = *(const f16x8*)(&Vs[32 + l31][ks * 16 + hi * 8]);
      oL = __builtin_amdgcn_mfma_f32_32x32x16_f16(v0, pa, oL, 0, 0, 0);
      oH = __builtin_amdgcn_mfma_f32_32x32x16_f16(v1, pa, oH, 0, 0, 0);
      osum = __builtin_amdgcn_mfma_f32_32x32x16_f16(ones8, pa, osum, 0, 0, 0);
    }
    __builtin_amdgcn_s_setprio(0);
  };

  // prologue: tile 0 -> regs
  kst0 = *(const u32x4*)(Kp);
  kst1 = *(const u32x4*)(Kp + 8);
  vst0 = *(const u32x4*)(Vp);
  vst1 = *(const u32x4*)(Vp + 8);
  Kp += (size_t)64 * D_;
  Vp += 64;

  // main loop: tiles 0 .. ntiles-2 (unconditional prefetch; mask only on a wave's tdiag)
#pragma unroll 1
  for (int t = 0; t < ntiles - 1; ++t) {
    __syncthreads();  // previous tile's readers done
    *(u32x4*)(&Ks[srow][sc]) = kst0;
    *(u32x4*)(&Ks[srow][sc + 8]) = kst1;
    *(u32x4*)(&Vs[srow][sc]) = vst0;
    *(u32x4*)(&Vs[srow][sc + 8]) = vst1;
    __syncthreads();  // writes visible
    kst0 = *(const u32x4*)(Kp);
    kst1 = *(const u32x4*)(Kp + 8);
    vst0 = *(const u32x4*)(Vp);
    vst1 = *(const u32x4*)(Vp + 8);
    Kp += (size_t)64 * D_;
    Vp += 64;
    if (t <= tdiag) tile_body(t * 64, t == tdiag);
  }

  // peeled final tile (waves with tdiag == ntiles-1 compute with mask; others idle)
  __syncthreads();
  *(u32x4*)(&Ks[srow][sc]) = kst0;
  *(u32x4*)(&Ks[srow][sc + 8]) = kst1;
  *(u32x4*)(&Vs[srow][sc]) = vst0;
  *(u32x4*)(&Vs[srow][sc + 8]) = vst1;
  __syncthreads();
  if (tdiag == ntiles - 1) tile_body((ntiles - 1) * 64, true);

  // ---- epilogue: normalize (lane-local), transpose via LDS scratch, coalesced store ----
  float inv = 1.0f / osum[0];
  __syncthreads();  // all waves done reading Ks/Vs
  u16* scr = (wave < 2) ? &Ks[wave * 32 + l31][0] : (u16*)&Vs[(wave - 2) * 32 + l31][0];
#pragma unroll
  for (int a = 0; a < 4; ++a) {
    u16x4 pl = {f2bf(oL[4 * a + 0] * inv), f2bf(oL[4 * a + 1] * inv),
                f2bf(oL[4 * a + 2] * inv), f2bf(oL[4 * a + 3] * inv)};
    *(u16x4*)(scr + 8 * a + 4 * hi) = pl;
    u16x4 ph = {f2bf(oH[4 * a + 0] * inv), f2bf(oH[4 * a + 1] * inv),
                f2bf(oH[4 * a + 2] * inv), f2bf(oH[4 * a + 3] * inv)};
    *(u16x4*)(scr + 32 + 8 * a + 4 * hi) = ph;
  }
  asm volatile("s_waitcnt lgkmcnt(0)" ::: "memory");
  const u16* srd = ((wave < 2) ? &Ks[wave * 32 + l31][0] : (u16*)&Vs[(wave - 2) * 32 + l31][0]) + hi * 32;
  u16* Og = attnb + (size_t)(b * S_ + wq0 + l31) * D_ + h * HD_ + hi * 32;
#pragma unroll
  for (int c = 0; c < 4; ++c)
    *(u32x4*)(Og + c * 8) = *(const u32x4*)(srd + c * 8);
}

// ---------------- output projection GEMM (fp32 out + bias, XCD-clustered swizzle) ----------------
__global__ __launch_bounds__(256) void out_gemm_kernel(const u16* __restrict__ attnb, const u16* __restrict__ Wot,
                                                       const float* __restrict__ bo, float* __restrict__ outp) {
  __shared__ u16 As[128 * 64];
  __shared__ u16 Bs[128 * 64];
  int lin = blockIdx.x;
  int xcd = lin & 7, pos = lin >> 3;  // pos in [0,64)
  int by = xcd * 8 + (pos >> 3);
  int bx = pos & 7;
  f32x4 acc[4][4] = {};
  int row0 = by * 128, col0 = bx * 128;
  gemm_main(attnb, Wot, As, Bs, row0, col0, acc);
  int lane = threadIdx.x & 63, wave = threadIdx.x >> 6;
  int wr = wave >> 1, wc = wave & 1, l15 = lane & 15, lg = lane >> 4;
  int rbase = row0 + wr * 64 + lg * 4, cbase = col0 + wc * 64 + l15;
#pragma unroll
  for (int n = 0; n < 4; ++n) {
    float bn = bo[cbase + n * 16];
#pragma unroll
    for (int m = 0; m < 4; ++m)
#pragma unroll
      for (int r = 0; r < 4; ++r)
        outp[(size_t)(rbase + m * 16 + r) * D_ + cbase + n * 16] = acc[m][n][r] + bn;
  }
}

extern "C" void kernel_launch(void* const* d_in, const int* in_sizes, int n_in,
                              void* d_out, int out_size, void* d_ws, size_t ws_size,
                              hipStream_t stream) {
  const float* x  = (const float*)d_in[0];
  const float* Wq = (const float*)d_in[1];
  const float* Wk = (const float*)d_in[2];
  const float* Wv = (const float*)d_in[3];
  const float* Wo = (const float*)d_in[4];
  const float* bo = (const float*)d_in[5];
  float* outp = (float*)d_out;

  char* ws = (char*)d_ws;
  u16* xb        = (u16*)(ws);                          // 16 MiB
  u16* Wqt       = (u16*)(ws + ((size_t)16 << 20));     // 2 MiB
  u16* Wkt       = (u16*)(ws + ((size_t)18 << 20));
  u16* Wvt       = (u16*)(ws + ((size_t)20 << 20));
  u16* Wot       = (u16*)(ws + ((size_t)22 << 20));
  u16* Qb        = (u16*)(ws + ((size_t)24 << 20));     // 16 MiB
  u16* Kb        = (u16*)(ws + ((size_t)40 << 20));     // 16 MiB
  _Float16* Vt   = (_Float16*)(ws + ((size_t)56 << 20));// 16 MiB
  u16* attnb     = (u16*)(ws + ((size_t)72 << 20));     // 16 MiB

  prep_kernel<<<dim3(9216), dim3(256), 0, stream>>>(x, xb, Wq, Wk, Wv, Wo, Wqt, Wkt, Wvt, Wot);
  qkv_gemm_kernel<<<dim3(1536), dim3(256), 0, stream>>>(xb, Wqt, Wkt, Wvt, Qb, Kb, Vt);
  attn_kernel<<<dim3(1024), dim3(256), 0, stream>>>(Qb, Kb, Vt, attnb);
  out_gemm_kernel<<<dim3(512), dim3(256), 0, stream>>>(attnb, Wot, bo, outp);
}

// Round 21
// 184.444 us; speedup vs baseline: 1.0243x; 1.0243x over previous
//
#include <hip/hip_runtime.h>

typedef unsigned short u16;
typedef unsigned int u32;
typedef __attribute__((ext_vector_type(4))) float f32x4;
typedef __attribute__((ext_vector_type(16))) float f32x16;
typedef __attribute__((ext_vector_type(8))) __bf16 bf16x8;
typedef __attribute__((ext_vector_type(4))) _Float16 f16x4;
typedef __attribute__((ext_vector_type(8))) _Float16 f16x8;
typedef __attribute__((ext_vector_type(4))) u16 u16x4;
typedef __attribute__((ext_vector_type(4))) u32 u32x4;
typedef __attribute__((ext_vector_type(2))) u32 u32x2;

#define D_ 1024
#define S_ 2048
#define B_ 4
#define H_ 16
#define HD_ 64
#define M_ 8192
#define LDP 72
#define QSCALE 0.18033688011112042591f /* 0.125 * log2(e) */

__device__ __forceinline__ u16 f2bf(float f) {
  u32 u = __float_as_uint(f);
  u += 0x7fffu + ((u >> 16) & 1u);
  return (u16)(u >> 16);
}

__device__ __forceinline__ float max3f(float a, float b, float c) {
  return fmaxf(fmaxf(a, b), c);  // clang fuses to v_max3_f32
}

// async 16B global->LDS DMA; LDS dest = wave-uniform base + lane*16 (linear!)
__device__ __forceinline__ void gload_lds16(const void* g, void* l) {
  __builtin_amdgcn_global_load_lds((const __attribute__((address_space(1))) void*)g,
                                   (__attribute__((address_space(3))) void*)l, 16, 0, 0);
}

// ---------------- fused prep: cast x (fp32->bf16) + transpose+cast weights ----------------
__global__ __launch_bounds__(256) void prep_kernel(const float* __restrict__ x, u16* __restrict__ xb,
                                                   const float* __restrict__ Wq, const float* __restrict__ Wk,
                                                   const float* __restrict__ Wv, const float* __restrict__ Wo,
                                                   u16* __restrict__ Wqt, u16* __restrict__ Wkt,
                                                   u16* __restrict__ Wvt, u16* __restrict__ Wot) {
  __shared__ float lds[64][65];
  int lin = blockIdx.x;
  if (lin < 8192) {
    int i = (lin * 256 + threadIdx.x) * 4;
    f32x4 v = *(const f32x4*)(x + i);
    u16x4 o = {f2bf(v[0]), f2bf(v[1]), f2bf(v[2]), f2bf(v[3])};
    *(u16x4*)(xb + i) = o;
    return;
  }
  int pos = lin - 8192;
  int z = pos >> 8, rem = pos & 255;
  const float* W = z == 0 ? Wq : z == 1 ? Wk : z == 2 ? Wv : Wo;
  u16* Wt       = z == 0 ? Wqt : z == 1 ? Wkt : z == 2 ? Wvt : Wot;
  int k0 = (rem >> 4) * 64, n0 = (rem & 15) * 64;
  int tr = threadIdx.x >> 6, tc = threadIdx.x & 63;
#pragma unroll
  for (int i = 0; i < 16; ++i)
    lds[tr + i * 4][tc] = W[(size_t)(k0 + tr + i * 4) * D_ + n0 + tc];
  __syncthreads();
#pragma unroll
  for (int i = 0; i < 16; ++i)
    Wt[(size_t)(n0 + tr + i * 4) * D_ + k0 + tc] = f2bf(lds[tc][tr + i * 4]);
}

// ---------------- shared 128x128 GEMM mainloop (global_load_lds staging, XOR swizzle) ----------------
__device__ __forceinline__ void gemm_main(const u16* __restrict__ A, const u16* __restrict__ Bt,
                                          u16* As, u16* Bs, int row0, int col0, f32x4 acc[4][4]) {
  const int tid = threadIdx.x;
  const int lane = tid & 63, wave = tid >> 6;
  const int wr = wave >> 1, wc = wave & 1;
  const int l15 = lane & 15, lg = lane >> 4;
  const int sr8 = lane >> 3;        // row within this wave's 8-row chunk (= r&7)
  const int scx = (lane & 7) ^ sr8; // pre-swizzled source k-chunk
#pragma unroll 1
  for (int k0 = 0; k0 < D_; k0 += 64) {
    // issue async stages: 4 wave-chunks of 8 rows for A and B each
#pragma unroll
    for (int it = 0; it < 4; ++it) {
      int rbase = (it * 4 + wave) * 8;
      int r = rbase + sr8;
      gload_lds16(A + (size_t)(row0 + r) * D_ + k0 + scx * 8, As + rbase * 64);
      gload_lds16(Bt + (size_t)(col0 + r) * D_ + k0 + scx * 8, Bs + rbase * 64);
    }
    __syncthreads();  // drains vmcnt -> DMA writes visible; syncs waves
#pragma unroll
    for (int kk = 0; kk < 64; kk += 32) {
      const int cb = kk >> 3;  // 0 or 4
      bf16x8 af[4], bf[4];
#pragma unroll
      for (int m = 0; m < 4; ++m) {
        int row = wr * 64 + m * 16 + l15;
        af[m] = *(const bf16x8*)(As + row * 64 + (((cb + lg) ^ (l15 & 7)) << 3));
      }
#pragma unroll
      for (int n = 0; n < 4; ++n) {
        int row = wc * 64 + n * 16 + l15;
        bf[n] = *(const bf16x8*)(Bs + row * 64 + (((cb + lg) ^ (l15 & 7)) << 3));
      }
#pragma unroll
      for (int m = 0; m < 4; ++m)
#pragma unroll
        for (int n = 0; n < 4; ++n)
          acc[m][n] = __builtin_amdgcn_mfma_f32_16x16x32_bf16(af[m], bf[n], acc[m][n], 0, 0, 0);
    }
    __syncthreads();  // readers done before next iteration's DMA writes
  }
}

// ---------------- QKV projection GEMM (1D grid, XCD-clustered swizzle) ----------------
__global__ __launch_bounds__(256) void qkv_gemm_kernel(const u16* __restrict__ xb,
                                                       const u16* __restrict__ Wqt, const u16* __restrict__ Wkt,
                                                       const u16* __restrict__ Wvt,
                                                       u16* __restrict__ Qb, u16* __restrict__ Kb,
                                                       _Float16* __restrict__ Vt) {
  __shared__ u16 As[128 * 64];
  __shared__ u16 Bs[128 * 64];
  int lin = blockIdx.x;
  int xcd = lin & 7, pos = lin >> 3;      // pos in [0,192)
  int mode = pos / 64;                    // z outer
  int rem = pos & 63;
  int by = xcd * 8 + (rem >> 3);          // row-panel
  int bx = rem & 7;                       // col-tile
  const u16* Bt = mode == 0 ? Wqt : mode == 1 ? Wkt : Wvt;
  f32x4 acc[4][4] = {};
  int row0 = by * 128, col0 = bx * 128;
  gemm_main(xb, Bt, As, Bs, row0, col0, acc);
  int lane = threadIdx.x & 63, wave = threadIdx.x >> 6;
  int wr = wave >> 1, wc = wave & 1, l15 = lane & 15, lg = lane >> 4;
  int rbase = row0 + wr * 64 + lg * 4, cbase = col0 + wc * 64 + l15;
  if (mode == 2) {
#pragma unroll
    for (int m = 0; m < 4; ++m) {
      int row = rbase + m * 16;
      int b = row >> 11, s = row & (S_ - 1);
#pragma unroll
      for (int n = 0; n < 4; ++n) {
        int col = cbase + n * 16;
        int h = col >> 6, hd = col & 63;
        f16x4 vv = {(_Float16)acc[m][n][0], (_Float16)acc[m][n][1],
                    (_Float16)acc[m][n][2], (_Float16)acc[m][n][3]};
        *(f16x4*)(Vt + ((size_t)((b << 4) + h) * HD_ + hd) * S_ + s) = vv;
      }
    }
  } else {
    u16* dst = mode == 0 ? Qb : Kb;
    float scl = mode == 0 ? QSCALE : 1.0f;
#pragma unroll
    for (int m = 0; m < 4; ++m)
#pragma unroll
      for (int n = 0; n < 4; ++n) {
        int col = cbase + n * 16;
#pragma unroll
        for (int r = 0; r < 4; ++r) {
          int row = rbase + m * 16 + r;
          dst[(size_t)row * D_ + col] = f2bf(acc[m][n][r] * scl);
        }
      }
  }
}

// ---------------- fused causal flash attention, v15 (r19-exact: best measured, 89.8us) ----------------
// Block = 2 waves / 128 threads / 64 q rows; 2048 blocks (qblk x bh), LPT, XCD clustering,
// single-buffer 18KB LDS, 2-barrier tile loop with reg-staged prefetch.
// Main loop: no mask code, unconditional prefetch. Final (diagonal) tile peeled.
// Row-sum via ones-MFMA (osum f32x16; spans both lane-halves -> no cross-half reduce).
__global__ __launch_bounds__(128) void attn_kernel(const u16* __restrict__ Qb, const u16* __restrict__ Kb,
                                                   const _Float16* __restrict__ Vt, u16* __restrict__ attnb) {
  __shared__ u16 Ks[64][LDP];       // [kv][hd]
  __shared__ _Float16 Vs[64][LDP];  // [hd][kv]
  const int tid = threadIdx.x;
  const int wave = tid >> 6, lane = tid & 63;
  const int l31 = lane & 31, hi = lane >> 5;
  const int lin = blockIdx.x;
  const int xcd = lin & 7, slot = lin >> 3;   // slot 0..255
  const int qblk = 31 - (slot >> 3);          // LPT: biggest first
  const int bh = (slot & 7) * 8 + xcd;        // bh&7 == xcd
  const int b = bh >> 4, h = bh & 15;
  const int ntiles = qblk + 1;
  const int wq0 = qblk * 64 + wave * 32;      // wave's rows [wq0, wq0+32)
  const int qg = wq0 + l31;                   // this lane's q row

  // staging: thread covers K/V row (tid>>1), 32-elem half (tid&1)*32
  const int srow = tid >> 1;
  const int sh = (tid & 1) * 32;
  const u16* Kp = Kb + (size_t)(b * S_ + srow) * D_ + h * HD_ + sh;
  const _Float16* Vp = Vt + ((size_t)bh * HD_ + srow) * S_ + sh;

  // Q B-fragments per 16-wide d-step
  const u16* Qrow = Qb + (size_t)(b * S_ + qg) * D_ + h * HD_;
  bf16x8 qf[4];
#pragma unroll
  for (int ds = 0; ds < 4; ++ds)
    qf[ds] = *(const bf16x8*)(Qrow + ds * 16 + hi * 8);

  float m = -1e30f;
  f32x16 oL = {}, oH = {};   // o^T rows hd 0..31 / 32..63, col q = l31
  f32x16 osum = {};          // ones-MFMA row-sum: every reg == Σ P for col q = l31
  const f16x8 ones8 = {(_Float16)1.f, (_Float16)1.f, (_Float16)1.f, (_Float16)1.f,
                       (_Float16)1.f, (_Float16)1.f, (_Float16)1.f, (_Float16)1.f};
  u32x4 kst[4], vst[4];

  // tile body (domask is compile-time constant at each inlined call site)
  auto tile_body = [&](int kvb, bool domask) {
    f32x16 sA = {}, sB = {};
    __builtin_amdgcn_s_setprio(1);
#pragma unroll
    for (int ds = 0; ds < 4; ++ds) {
      bf16x8 k0 = *(const bf16x8*)(&Ks[l31][ds * 16 + hi * 8]);
      bf16x8 k1 = *(const bf16x8*)(&Ks[32 + l31][ds * 16 + hi * 8]);
      sA = __builtin_amdgcn_mfma_f32_32x32x16_bf16(k0, qf[ds], sA, 0, 0, 0);
      sB = __builtin_amdgcn_mfma_f32_32x32x16_bf16(k1, qf[ds], sB, 0, 0, 0);
    }
    __builtin_amdgcn_s_setprio(0);
    if (domask) {
#pragma unroll
      for (int r = 0; r < 16; ++r) {
        int off = (r & 3) + 8 * (r >> 2) + 4 * hi;
        if (kvb + off > qg) sA[r] = -1e30f;
        if (kvb + 32 + off > qg) sB[r] = -1e30f;
      }
    }
    float mx[16];
#pragma unroll
    for (int r = 0; r < 16; ++r) mx[r] = fmaxf(sA[r], sB[r]);
    float y0 = max3f(mx[0], mx[1], mx[2]);
    float y1 = max3f(mx[3], mx[4], mx[5]);
    float y2 = max3f(mx[6], mx[7], mx[8]);
    float y3 = max3f(mx[9], mx[10], mx[11]);
    float y4 = max3f(mx[12], mx[13], mx[14]);
    float tmax = fmaxf(max3f(y0, y1, y2), max3f(y3, y4, mx[15]));
    tmax = fmaxf(tmax, __shfl_xor(tmax, 32));
    if (!__all(tmax - m <= 8.f)) {  // defer-max (T13)
      float nm = fmaxf(m, tmax);
      float alpha = exp2f(m - nm);
      m = nm;
      osum *= alpha;
      oL *= alpha;
      oH *= alpha;
    }
#pragma unroll
    for (int r = 0; r < 16; ++r) {
      sA[r] = exp2f(sA[r] - m);
      sB[r] = exp2f(sB[r] - m);
    }
    u32 uA[8], uB[8], vA[8], vB[8];
#pragma unroll
    for (int k = 0; k < 8; ++k) {
      uA[k] = __builtin_bit_cast(u32, __builtin_amdgcn_cvt_pkrtz(sA[2 * k], sA[2 * k + 1]));
      uB[k] = __builtin_bit_cast(u32, __builtin_amdgcn_cvt_pkrtz(sB[2 * k], sB[2 * k + 1]));
    }
#pragma unroll
    for (int k = 0; k < 8; ++k) {
      vA[k] = __shfl_xor(uA[k], 32);
      vB[k] = __shfl_xor(uB[k], 32);
    }
    __builtin_amdgcn_s_setprio(1);
#pragma unroll
    for (int ks = 0; ks < 4; ++ks) {
      const u32* U = (ks >> 1) ? uB : uA;
      const u32* Vw = (ks >> 1) ? vB : vA;
      const int b4 = (ks & 1) * 4;
      u32 w0 = hi ? Vw[b4 + 2] : U[b4 + 0];
      u32 w1 = hi ? Vw[b4 + 3] : U[b4 + 1];
      u32 w2 = hi ? U[b4 + 2] : Vw[b4 + 0];
      u32 w3 = hi ? U[b4 + 3] : Vw[b4 + 1];
      f16x8 pa = __builtin_bit_cast(f16x8, (u32x4){w0, w1, w2, w3});
      f16x8 v0 = *(const f16x8*)(&Vs[l31][ks * 16 + hi * 8]);
      f16x8 v1 = *(const f16x8*)(&Vs[32 + l31][ks * 16 + hi * 8]);
      oL = __builtin_amdgcn_mfma_f32_32x32x16_f16(v0, pa, oL, 0, 0, 0);
      oH = __builtin_amdgcn_mfma_f32_32x32x16_f16(v1, pa, oH, 0, 0, 0);
      osum = __builtin_amdgcn_mfma_f32_32x32x16_f16(ones8, pa, osum, 0, 0, 0);
    }
    __builtin_amdgcn_s_setprio(0);
  };

  // prologue: tile 0 -> regs
#pragma unroll
  for (int c = 0; c < 4; ++c) {
    kst[c] = *(const u32x4*)(Kp + c * 8);
    vst[c] = *(const u32x4*)(Vp + c * 8);
  }
  Kp += (size_t)64 * D_;
  Vp += 64;

  // main loop: tiles 0 .. ntiles-2 (no mask, unconditional prefetch)
#pragma unroll 1
  for (int t = 0; t < ntiles - 1; ++t) {
    __syncthreads();  // previous tile's readers done
#pragma unroll
    for (int c = 0; c < 4; ++c) {
      *(u32x4*)(&Ks[srow][sh + c * 8]) = kst[c];
      *(u32x4*)(&Vs[srow][sh + c * 8]) = vst[c];
    }
    __syncthreads();  // writes visible
#pragma unroll
    for (int c = 0; c < 4; ++c) {
      kst[c] = *(const u32x4*)(Kp + c * 8);
      vst[c] = *(const u32x4*)(Vp + c * 8);
    }
    Kp += (size_t)64 * D_;
    Vp += 64;
    tile_body(t * 64, false);
  }

  // peeled final (diagonal) tile
  __syncthreads();
#pragma unroll
  for (int c = 0; c < 4; ++c) {
    *(u32x4*)(&Ks[srow][sh + c * 8]) = kst[c];
    *(u32x4*)(&Vs[srow][sh + c * 8]) = vst[c];
  }
  __syncthreads();
  tile_body((ntiles - 1) * 64, true);

  // ---- epilogue: normalize (osum spans both halves -> lane-local), transpose via K-LDS ----
  float inv = 1.0f / osum[0];
  __syncthreads();  // both waves done reading Ks/Vs
  u16* scr = &Ks[wave * 32 + l31][0];  // scratch row = this lane's q
#pragma unroll
  for (int a = 0; a < 4; ++a) {
    u16x4 pl = {f2bf(oL[4 * a + 0] * inv), f2bf(oL[4 * a + 1] * inv),
                f2bf(oL[4 * a + 2] * inv), f2bf(oL[4 * a + 3] * inv)};
    *(u16x4*)(scr + 8 * a + 4 * hi) = pl;
    u16x4 ph = {f2bf(oH[4 * a + 0] * inv), f2bf(oH[4 * a + 1] * inv),
                f2bf(oH[4 * a + 2] * inv), f2bf(oH[4 * a + 3] * inv)};
    *(u16x4*)(scr + 32 + 8 * a + 4 * hi) = ph;
  }
  asm volatile("s_waitcnt lgkmcnt(0)" ::: "memory");
  const u16* srd = &Ks[wave * 32 + l31][hi * 32];
  u16* Og = attnb + (size_t)(b * S_ + wq0 + l31) * D_ + h * HD_ + hi * 32;
#pragma unroll
  for (int c = 0; c < 4; ++c)
    *(u32x4*)(Og + c * 8) = *(const u32x4*)(srd + c * 8);
}

// ---------------- output projection GEMM (fp32 out + bias, XCD-clustered swizzle) ----------------
__global__ __launch_bounds__(256) void out_gemm_kernel(const u16* __restrict__ attnb, const u16* __restrict__ Wot,
                                                       const float* __restrict__ bo, float* __restrict__ outp) {
  __shared__ u16 As[128 * 64];
  __shared__ u16 Bs[128 * 64];
  int lin = blockIdx.x;
  int xcd = lin & 7, pos = lin >> 3;  // pos in [0,64)
  int by = xcd * 8 + (pos >> 3);
  int bx = pos & 7;
  f32x4 acc[4][4] = {};
  int row0 = by * 128, col0 = bx * 128;
  gemm_main(attnb, Wot, As, Bs, row0, col0, acc);
  int lane = threadIdx.x & 63, wave = threadIdx.x >> 6;
  int wr = wave >> 1, wc = wave & 1, l15 = lane & 15, lg = lane >> 4;
  int rbase = row0 + wr * 64 + lg * 4, cbase = col0 + wc * 64 + l15;
#pragma unroll
  for (int n = 0; n < 4; ++n) {
    float bn = bo[cbase + n * 16];
#pragma unroll
    for (int m = 0; m < 4; ++m)
#pragma unroll
      for (int r = 0; r < 4; ++r)
        outp[(size_t)(rbase + m * 16 + r) * D_ + cbase + n * 16] = acc[m][n][r] + bn;
  }
}

extern "C" void kernel_launch(void* const* d_in, const int* in_sizes, int n_in,
                              void* d_out, int out_size, void* d_ws, size_t ws_size,
                              hipStream_t stream) {
  const float* x  = (const float*)d_in[0];
  const float* Wq = (const float*)d_in[1];
  const float* Wk = (const float*)d_in[2];
  const float* Wv = (const float*)d_in[3];
  const float* Wo = (const float*)d_in[4];
  const float* bo = (const float*)d_in[5];
  float* outp = (float*)d_out;

  char* ws = (char*)d_ws;
  u16* xb        = (u16*)(ws);                          // 16 MiB
  u16* Wqt       = (u16*)(ws + ((size_t)16 << 20));     // 2 MiB
  u16* Wkt       = (u16*)(ws + ((size_t)18 << 20));
  u16* Wvt       = (u16*)(ws + ((size_t)20 << 20));
  u16* Wot       = (u16*)(ws + ((size_t)22 << 20));
  u16* Qb        = (u16*)(ws + ((size_t)24 << 20));     // 16 MiB
  u16* Kb        = (u16*)(ws + ((size_t)40 << 20));     // 16 MiB
  _Float16* Vt   = (_Float16*)(ws + ((size_t)56 << 20));// 16 MiB
  u16* attnb     = (u16*)(ws + ((size_t)72 << 20));     // 16 MiB

  prep_kernel<<<dim3(9216), dim3(256), 0, stream>>>(x, xb, Wq, Wk, Wv, Wo, Wqt, Wkt, Wvt, Wot);
  qkv_gemm_kernel<<<dim3(1536), dim3(256), 0, stream>>>(xb, Wqt, Wkt, Wvt, Qb, Kb, Vt);
  attn_kernel<<<dim3(2048), dim3(128), 0, stream>>>(Qb, Kb, Vt, attnb);
  out_gemm_kernel<<<dim3(512), dim3(256), 0, stream>>>(attnb, Wot, bo, outp);
}

// Round 22
// 180.898 us; speedup vs baseline: 1.0444x; 1.0196x over previous
//
#include <hip/hip_runtime.h>

typedef unsigned short u16;
typedef unsigned int u32;
typedef __attribute__((ext_vector_type(4))) float f32x4;
typedef __attribute__((ext_vector_type(16))) float f32x16;
typedef __attribute__((ext_vector_type(8))) __bf16 bf16x8;
typedef __attribute__((ext_vector_type(4))) _Float16 f16x4;
typedef __attribute__((ext_vector_type(8))) _Float16 f16x8;
typedef __attribute__((ext_vector_type(4))) u16 u16x4;
typedef __attribute__((ext_vector_type(4))) u32 u32x4;
typedef __attribute__((ext_vector_type(2))) u32 u32x2;

#define D_ 1024
#define S_ 2048
#define B_ 4
#define H_ 16
#define HD_ 64
#define M_ 8192
#define LDP 72
#define QSCALE 0.18033688011112042591f /* 0.125 * log2(e) */

__device__ __forceinline__ u16 f2bf(float f) {
  u32 u = __float_as_uint(f);
  u += 0x7fffu + ((u >> 16) & 1u);
  return (u16)(u >> 16);
}

__device__ __forceinline__ float max3f(float a, float b, float c) {
  return fmaxf(fmaxf(a, b), c);  // clang fuses to v_max3_f32
}

// async 16B global->LDS DMA; LDS dest = wave-uniform base + lane*16 (linear!)
__device__ __forceinline__ void gload_lds16(const void* g, void* l) {
  __builtin_amdgcn_global_load_lds((const __attribute__((address_space(1))) void*)g,
                                   (__attribute__((address_space(3))) void*)l, 16, 0, 0);
}

// ---------------- fused prep: cast x (fp32->bf16) + transpose+cast weights ----------------
__global__ __launch_bounds__(256) void prep_kernel(const float* __restrict__ x, u16* __restrict__ xb,
                                                   const float* __restrict__ Wq, const float* __restrict__ Wk,
                                                   const float* __restrict__ Wv, const float* __restrict__ Wo,
                                                   u16* __restrict__ Wqt, u16* __restrict__ Wkt,
                                                   u16* __restrict__ Wvt, u16* __restrict__ Wot) {
  __shared__ float lds[64][65];
  int lin = blockIdx.x;
  if (lin < 8192) {
    int i = (lin * 256 + threadIdx.x) * 4;
    f32x4 v = *(const f32x4*)(x + i);
    u16x4 o = {f2bf(v[0]), f2bf(v[1]), f2bf(v[2]), f2bf(v[3])};
    *(u16x4*)(xb + i) = o;
    return;
  }
  int pos = lin - 8192;
  int z = pos >> 8, rem = pos & 255;
  const float* W = z == 0 ? Wq : z == 1 ? Wk : z == 2 ? Wv : Wo;
  u16* Wt       = z == 0 ? Wqt : z == 1 ? Wkt : z == 2 ? Wvt : Wot;
  int k0 = (rem >> 4) * 64, n0 = (rem & 15) * 64;
  int tr = threadIdx.x >> 6, tc = threadIdx.x & 63;
#pragma unroll
  for (int i = 0; i < 16; ++i)
    lds[tr + i * 4][tc] = W[(size_t)(k0 + tr + i * 4) * D_ + n0 + tc];
  __syncthreads();
#pragma unroll
  for (int i = 0; i < 16; ++i)
    Wt[(size_t)(n0 + tr + i * 4) * D_ + k0 + tc] = f2bf(lds[tc][tr + i * 4]);
}

// ---------------- shared 128x128 GEMM mainloop (global_load_lds staging, XOR swizzle) ----------------
__device__ __forceinline__ void gemm_main(const u16* __restrict__ A, const u16* __restrict__ Bt,
                                          u16* As, u16* Bs, int row0, int col0, f32x4 acc[4][4]) {
  const int tid = threadIdx.x;
  const int lane = tid & 63, wave = tid >> 6;
  const int wr = wave >> 1, wc = wave & 1;
  const int l15 = lane & 15, lg = lane >> 4;
  const int sr8 = lane >> 3;        // row within this wave's 8-row chunk (= r&7)
  const int scx = (lane & 7) ^ sr8; // pre-swizzled source k-chunk
#pragma unroll 1
  for (int k0 = 0; k0 < D_; k0 += 64) {
    // issue async stages: 4 wave-chunks of 8 rows for A and B each
#pragma unroll
    for (int it = 0; it < 4; ++it) {
      int rbase = (it * 4 + wave) * 8;
      int r = rbase + sr8;
      gload_lds16(A + (size_t)(row0 + r) * D_ + k0 + scx * 8, As + rbase * 64);
      gload_lds16(Bt + (size_t)(col0 + r) * D_ + k0 + scx * 8, Bs + rbase * 64);
    }
    __syncthreads();  // drains vmcnt -> DMA writes visible; syncs waves
#pragma unroll
    for (int kk = 0; kk < 64; kk += 32) {
      const int cb = kk >> 3;  // 0 or 4
      bf16x8 af[4], bf[4];
#pragma unroll
      for (int m = 0; m < 4; ++m) {
        int row = wr * 64 + m * 16 + l15;
        af[m] = *(const bf16x8*)(As + row * 64 + (((cb + lg) ^ (l15 & 7)) << 3));
      }
#pragma unroll
      for (int n = 0; n < 4; ++n) {
        int row = wc * 64 + n * 16 + l15;
        bf[n] = *(const bf16x8*)(Bs + row * 64 + (((cb + lg) ^ (l15 & 7)) << 3));
      }
#pragma unroll
      for (int m = 0; m < 4; ++m)
#pragma unroll
        for (int n = 0; n < 4; ++n)
          acc[m][n] = __builtin_amdgcn_mfma_f32_16x16x32_bf16(af[m], bf[n], acc[m][n], 0, 0, 0);
    }
    __syncthreads();  // readers done before next iteration's DMA writes
  }
}

// ---------------- QKV projection GEMM (1D grid, XCD-clustered swizzle) ----------------
__global__ __launch_bounds__(256) void qkv_gemm_kernel(const u16* __restrict__ xb,
                                                       const u16* __restrict__ Wqt, const u16* __restrict__ Wkt,
                                                       const u16* __restrict__ Wvt,
                                                       u16* __restrict__ Qb, u16* __restrict__ Kb,
                                                       _Float16* __restrict__ Vt) {
  __shared__ u16 As[128 * 64];
  __shared__ u16 Bs[128 * 64];
  int lin = blockIdx.x;
  int xcd = lin & 7, pos = lin >> 3;      // pos in [0,192)
  int mode = pos / 64;                    // z outer
  int rem = pos & 63;
  int by = xcd * 8 + (rem >> 3);          // row-panel
  int bx = rem & 7;                       // col-tile
  const u16* Bt = mode == 0 ? Wqt : mode == 1 ? Wkt : Wvt;
  f32x4 acc[4][4] = {};
  int row0 = by * 128, col0 = bx * 128;
  gemm_main(xb, Bt, As, Bs, row0, col0, acc);
  int lane = threadIdx.x & 63, wave = threadIdx.x >> 6;
  int wr = wave >> 1, wc = wave & 1, l15 = lane & 15, lg = lane >> 4;
  int rbase = row0 + wr * 64 + lg * 4, cbase = col0 + wc * 64 + l15;
  if (mode == 2) {
#pragma unroll
    for (int m = 0; m < 4; ++m) {
      int row = rbase + m * 16;
      int b = row >> 11, s = row & (S_ - 1);
#pragma unroll
      for (int n = 0; n < 4; ++n) {
        int col = cbase + n * 16;
        int h = col >> 6, hd = col & 63;
        f16x4 vv = {(_Float16)acc[m][n][0], (_Float16)acc[m][n][1],
                    (_Float16)acc[m][n][2], (_Float16)acc[m][n][3]};
        *(f16x4*)(Vt + ((size_t)((b << 4) + h) * HD_ + hd) * S_ + s) = vv;
      }
    }
  } else {
    u16* dst = mode == 0 ? Qb : Kb;
    float scl = mode == 0 ? QSCALE : 1.0f;
#pragma unroll
    for (int m = 0; m < 4; ++m)
#pragma unroll
      for (int n = 0; n < 4; ++n) {
        int col = cbase + n * 16;
#pragma unroll
        for (int r = 0; r < 4; ++r) {
          int row = rbase + m * 16 + r;
          dst[(size_t)row * D_ + col] = f2bf(acc[m][n][r] * scl);
        }
      }
  }
}

// ---------------- fused causal flash attention, v17: r19 + permlane32_swap P-redistribution ----------------
// Block = 2 waves / 128 threads / 64 q rows; 2048 blocks (qblk x bh), LPT, XCD clustering,
// single-buffer 18KB LDS, 2-barrier tile loop with reg-staged prefetch; peeled diagonal tile.
// P->B-fragment redistribution now uses v_permlane32_swap (VALU) instead of 16 ds_bpermute
// + 32 selects: swap(u[j], u[j+2]).out0 = w0 {lo_j | lo_j+2}, .out1 = w2 {hi_j | hi_j+2}.
__global__ __launch_bounds__(128) void attn_kernel(const u16* __restrict__ Qb, const u16* __restrict__ Kb,
                                                   const _Float16* __restrict__ Vt, u16* __restrict__ attnb) {
  __shared__ u16 Ks[64][LDP];       // [kv][hd]
  __shared__ _Float16 Vs[64][LDP];  // [hd][kv]
  const int tid = threadIdx.x;
  const int wave = tid >> 6, lane = tid & 63;
  const int l31 = lane & 31, hi = lane >> 5;
  const int lin = blockIdx.x;
  const int xcd = lin & 7, slot = lin >> 3;   // slot 0..255
  const int qblk = 31 - (slot >> 3);          // LPT: biggest first
  const int bh = (slot & 7) * 8 + xcd;        // bh&7 == xcd
  const int b = bh >> 4, h = bh & 15;
  const int ntiles = qblk + 1;
  const int wq0 = qblk * 64 + wave * 32;      // wave's rows [wq0, wq0+32)
  const int qg = wq0 + l31;                   // this lane's q row

  // staging: thread covers K/V row (tid>>1), 32-elem half (tid&1)*32
  const int srow = tid >> 1;
  const int sh = (tid & 1) * 32;
  const u16* Kp = Kb + (size_t)(b * S_ + srow) * D_ + h * HD_ + sh;
  const _Float16* Vp = Vt + ((size_t)bh * HD_ + srow) * S_ + sh;

  // Q B-fragments per 16-wide d-step
  const u16* Qrow = Qb + (size_t)(b * S_ + qg) * D_ + h * HD_;
  bf16x8 qf[4];
#pragma unroll
  for (int ds = 0; ds < 4; ++ds)
    qf[ds] = *(const bf16x8*)(Qrow + ds * 16 + hi * 8);

  float m = -1e30f;
  f32x16 oL = {}, oH = {};   // o^T rows hd 0..31 / 32..63, col q = l31
  f32x16 osum = {};          // ones-MFMA row-sum: every reg == Σ P for col q = l31
  const f16x8 ones8 = {(_Float16)1.f, (_Float16)1.f, (_Float16)1.f, (_Float16)1.f,
                       (_Float16)1.f, (_Float16)1.f, (_Float16)1.f, (_Float16)1.f};
  u32x4 kst[4], vst[4];

  // tile body (domask is compile-time constant at each inlined call site)
  auto tile_body = [&](int kvb, bool domask) {
    f32x16 sA = {}, sB = {};
    __builtin_amdgcn_s_setprio(1);
#pragma unroll
    for (int ds = 0; ds < 4; ++ds) {
      bf16x8 k0 = *(const bf16x8*)(&Ks[l31][ds * 16 + hi * 8]);
      bf16x8 k1 = *(const bf16x8*)(&Ks[32 + l31][ds * 16 + hi * 8]);
      sA = __builtin_amdgcn_mfma_f32_32x32x16_bf16(k0, qf[ds], sA, 0, 0, 0);
      sB = __builtin_amdgcn_mfma_f32_32x32x16_bf16(k1, qf[ds], sB, 0, 0, 0);
    }
    __builtin_amdgcn_s_setprio(0);
    if (domask) {
#pragma unroll
      for (int r = 0; r < 16; ++r) {
        int off = (r & 3) + 8 * (r >> 2) + 4 * hi;
        if (kvb + off > qg) sA[r] = -1e30f;
        if (kvb + 32 + off > qg) sB[r] = -1e30f;
      }
    }
    float mx[16];
#pragma unroll
    for (int r = 0; r < 16; ++r) mx[r] = fmaxf(sA[r], sB[r]);
    float y0 = max3f(mx[0], mx[1], mx[2]);
    float y1 = max3f(mx[3], mx[4], mx[5]);
    float y2 = max3f(mx[6], mx[7], mx[8]);
    float y3 = max3f(mx[9], mx[10], mx[11]);
    float y4 = max3f(mx[12], mx[13], mx[14]);
    float tmax = fmaxf(max3f(y0, y1, y2), max3f(y3, y4, mx[15]));
    tmax = fmaxf(tmax, __shfl_xor(tmax, 32));
    if (!__all(tmax - m <= 8.f)) {  // defer-max (T13)
      float nm = fmaxf(m, tmax);
      float alpha = exp2f(m - nm);
      m = nm;
      osum *= alpha;
      oL *= alpha;
      oH *= alpha;
    }
#pragma unroll
    for (int r = 0; r < 16; ++r) {
      sA[r] = exp2f(sA[r] - m);
      sB[r] = exp2f(sB[r] - m);
    }
    u32 uA[8], uB[8];
#pragma unroll
    for (int k = 0; k < 8; ++k) {
      uA[k] = __builtin_bit_cast(u32, __builtin_amdgcn_cvt_pkrtz(sA[2 * k], sA[2 * k + 1]));
      uB[k] = __builtin_bit_cast(u32, __builtin_amdgcn_cvt_pkrtz(sB[2 * k], sB[2 * k + 1]));
    }
    // permlane32_swap: out0 = {x_lo | y_lo}, out1 = {x_hi | y_hi} (lane-positioned).
    // Verified vs select logic: ks0.w0 = swap(u0,u2).out0, ks0.w2 = .out1, etc.
    u32 w[4][4];
    {
      auto pA0 = __builtin_amdgcn_permlane32_swap(uA[0], uA[2], false, false);
      auto pA1 = __builtin_amdgcn_permlane32_swap(uA[1], uA[3], false, false);
      w[0][0] = pA0[0]; w[0][1] = pA1[0]; w[0][2] = pA0[1]; w[0][3] = pA1[1];
      auto pA2 = __builtin_amdgcn_permlane32_swap(uA[4], uA[6], false, false);
      auto pA3 = __builtin_amdgcn_permlane32_swap(uA[5], uA[7], false, false);
      w[1][0] = pA2[0]; w[1][1] = pA3[0]; w[1][2] = pA2[1]; w[1][3] = pA3[1];
      auto pB0 = __builtin_amdgcn_permlane32_swap(uB[0], uB[2], false, false);
      auto pB1 = __builtin_amdgcn_permlane32_swap(uB[1], uB[3], false, false);
      w[2][0] = pB0[0]; w[2][1] = pB1[0]; w[2][2] = pB0[1]; w[2][3] = pB1[1];
      auto pB2 = __builtin_amdgcn_permlane32_swap(uB[4], uB[6], false, false);
      auto pB3 = __builtin_amdgcn_permlane32_swap(uB[5], uB[7], false, false);
      w[3][0] = pB2[0]; w[3][1] = pB3[0]; w[3][2] = pB2[1]; w[3][3] = pB3[1];
    }
    __builtin_amdgcn_s_setprio(1);
#pragma unroll
    for (int ks = 0; ks < 4; ++ks) {
      f16x8 pa = __builtin_bit_cast(f16x8, (u32x4){w[ks][0], w[ks][1], w[ks][2], w[ks][3]});
      f16x8 v0 = *(const f16x8*)(&Vs[l31][ks * 16 + hi * 8]);
      f16x8 v1 = *(const f16x8*)(&Vs[32 + l31][ks * 16 + hi * 8]);
      oL = __builtin_amdgcn_mfma_f32_32x32x16_f16(v0, pa, oL, 0, 0, 0);
      oH = __builtin_amdgcn_mfma_f32_32x32x16_f16(v1, pa, oH, 0, 0, 0);
      osum = __builtin_amdgcn_mfma_f32_32x32x16_f16(ones8, pa, osum, 0, 0, 0);
    }
    __builtin_amdgcn_s_setprio(0);
  };

  // prologue: tile 0 -> regs
#pragma unroll
  for (int c = 0; c < 4; ++c) {
    kst[c] = *(const u32x4*)(Kp + c * 8);
    vst[c] = *(const u32x4*)(Vp + c * 8);
  }
  Kp += (size_t)64 * D_;
  Vp += 64;

  // main loop: tiles 0 .. ntiles-2 (no mask, unconditional prefetch)
#pragma unroll 1
  for (int t = 0; t < ntiles - 1; ++t) {
    __syncthreads();  // previous tile's readers done
#pragma unroll
    for (int c = 0; c < 4; ++c) {
      *(u32x4*)(&Ks[srow][sh + c * 8]) = kst[c];
      *(u32x4*)(&Vs[srow][sh + c * 8]) = vst[c];
    }
    __syncthreads();  // writes visible
#pragma unroll
    for (int c = 0; c < 4; ++c) {
      kst[c] = *(const u32x4*)(Kp + c * 8);
      vst[c] = *(const u32x4*)(Vp + c * 8);
    }
    Kp += (size_t)64 * D_;
    Vp += 64;
    tile_body(t * 64, false);
  }

  // peeled final (diagonal) tile
  __syncthreads();
#pragma unroll
  for (int c = 0; c < 4; ++c) {
    *(u32x4*)(&Ks[srow][sh + c * 8]) = kst[c];
    *(u32x4*)(&Vs[srow][sh + c * 8]) = vst[c];
  }
  __syncthreads();
  tile_body((ntiles - 1) * 64, true);

  // ---- epilogue: normalize (osum spans both halves -> lane-local), transpose via K-LDS ----
  float inv = 1.0f / osum[0];
  __syncthreads();  // both waves done reading Ks/Vs
  u16* scr = &Ks[wave * 32 + l31][0];  // scratch row = this lane's q
#pragma unroll
  for (int a = 0; a < 4; ++a) {
    u16x4 pl = {f2bf(oL[4 * a + 0] * inv), f2bf(oL[4 * a + 1] * inv),
                f2bf(oL[4 * a + 2] * inv), f2bf(oL[4 * a + 3] * inv)};
    *(u16x4*)(scr + 8 * a + 4 * hi) = pl;
    u16x4 ph = {f2bf(oH[4 * a + 0] * inv), f2bf(oH[4 * a + 1] * inv),
                f2bf(oH[4 * a + 2] * inv), f2bf(oH[4 * a + 3] * inv)};
    *(u16x4*)(scr + 32 + 8 * a + 4 * hi) = ph;
  }
  asm volatile("s_waitcnt lgkmcnt(0)" ::: "memory");
  const u16* srd = &Ks[wave * 32 + l31][hi * 32];
  u16* Og = attnb + (size_t)(b * S_ + wq0 + l31) * D_ + h * HD_ + hi * 32;
#pragma unroll
  for (int c = 0; c < 4; ++c)
    *(u32x4*)(Og + c * 8) = *(const u32x4*)(srd + c * 8);
}

// ---------------- output projection GEMM (fp32 out + bias, XCD-clustered swizzle) ----------------
__global__ __launch_bounds__(256) void out_gemm_kernel(const u16* __restrict__ attnb, const u16* __restrict__ Wot,
                                                       const float* __restrict__ bo, float* __restrict__ outp) {
  __shared__ u16 As[128 * 64];
  __shared__ u16 Bs[128 * 64];
  int lin = blockIdx.x;
  int xcd = lin & 7, pos = lin >> 3;  // pos in [0,64)
  int by = xcd * 8 + (pos >> 3);
  int bx = pos & 7;
  f32x4 acc[4][4] = {};
  int row0 = by * 128, col0 = bx * 128;
  gemm_main(attnb, Wot, As, Bs, row0, col0, acc);
  int lane = threadIdx.x & 63, wave = threadIdx.x >> 6;
  int wr = wave >> 1, wc = wave & 1, l15 = lane & 15, lg = lane >> 4;
  int rbase = row0 + wr * 64 + lg * 4, cbase = col0 + wc * 64 + l15;
#pragma unroll
  for (int n = 0; n < 4; ++n) {
    float bn = bo[cbase + n * 16];
#pragma unroll
    for (int m = 0; m < 4; ++m)
#pragma unroll
      for (int r = 0; r < 4; ++r)
        outp[(size_t)(rbase + m * 16 + r) * D_ + cbase + n * 16] = acc[m][n][r] + bn;
  }
}

extern "C" void kernel_launch(void* const* d_in, const int* in_sizes, int n_in,
                              void* d_out, int out_size, void* d_ws, size_t ws_size,
                              hipStream_t stream) {
  const float* x  = (const float*)d_in[0];
  const float* Wq = (const float*)d_in[1];
  const float* Wk = (const float*)d_in[2];
  const float* Wv = (const float*)d_in[3];
  const float* Wo = (const float*)d_in[4];
  const float* bo = (const float*)d_in[5];
  float* outp = (float*)d_out;

  char* ws = (char*)d_ws;
  u16* xb        = (u16*)(ws);                          // 16 MiB
  u16* Wqt       = (u16*)(ws + ((size_t)16 << 20));     // 2 MiB
  u16* Wkt       = (u16*)(ws + ((size_t)18 << 20));
  u16* Wvt       = (u16*)(ws + ((size_t)20 << 20));
  u16* Wot       = (u16*)(ws + ((size_t)22 << 20));
  u16* Qb        = (u16*)(ws + ((size_t)24 << 20));     // 16 MiB
  u16* Kb        = (u16*)(ws + ((size_t)40 << 20));     // 16 MiB
  _Float16* Vt   = (_Float16*)(ws + ((size_t)56 << 20));// 16 MiB
  u16* attnb     = (u16*)(ws + ((size_t)72 << 20));     // 16 MiB

  prep_kernel<<<dim3(9216), dim3(256), 0, stream>>>(x, xb, Wq, Wk, Wv, Wo, Wqt, Wkt, Wvt, Wot);
  qkv_gemm_kernel<<<dim3(1536), dim3(256), 0, stream>>>(xb, Wqt, Wkt, Wvt, Qb, Kb, Vt);
  attn_kernel<<<dim3(2048), dim3(128), 0, stream>>>(Qb, Kb, Vt, attnb);
  out_gemm_kernel<<<dim3(512), dim3(256), 0, stream>>>(attnb, Wot, bo, outp);
}

// Round 24
// 180.892 us; speedup vs baseline: 1.0444x; 1.0000x over previous
//
#include <hip/hip_runtime.h>

typedef unsigned short u16;
typedef unsigned int u32;
typedef __attribute__((ext_vector_type(4))) float f32x4;
typedef __attribute__((ext_vector_type(16))) float f32x16;
typedef __attribute__((ext_vector_type(8))) __bf16 bf16x8;
typedef __attribute__((ext_vector_type(4))) _Float16 f16x4;
typedef __attribute__((ext_vector_type(8))) _Float16 f16x8;
typedef __attribute__((ext_vector_type(4))) u16 u16x4;
typedef __attribute__((ext_vector_type(4))) u32 u32x4;
typedef __attribute__((ext_vector_type(2))) u32 u32x2;

#define D_ 1024
#define S_ 2048
#define B_ 4
#define H_ 16
#define HD_ 64
#define M_ 8192
#define LDP 72
#define QSCALE 0.18033688011112042591f /* 0.125 * log2(e) */

__device__ __forceinline__ u16 f2bf(float f) {
  u32 u = __float_as_uint(f);
  u += 0x7fffu + ((u >> 16) & 1u);
  return (u16)(u >> 16);
}

__device__ __forceinline__ float max3f(float a, float b, float c) {
  return fmaxf(fmaxf(a, b), c);  // clang fuses to v_max3_f32
}

// async 16B global->LDS DMA; LDS dest = wave-uniform base + lane*16 (linear!)
__device__ __forceinline__ void gload_lds16(const void* g, void* l) {
  __builtin_amdgcn_global_load_lds((const __attribute__((address_space(1))) void*)g,
                                   (__attribute__((address_space(3))) void*)l, 16, 0, 0);
}

// ---------------- fused prep: cast x (fp32->bf16) + transpose+cast weights ----------------
__global__ __launch_bounds__(256) void prep_kernel(const float* __restrict__ x, u16* __restrict__ xb,
                                                   const float* __restrict__ Wq, const float* __restrict__ Wk,
                                                   const float* __restrict__ Wv, const float* __restrict__ Wo,
                                                   u16* __restrict__ Wqt, u16* __restrict__ Wkt,
                                                   u16* __restrict__ Wvt, u16* __restrict__ Wot) {
  __shared__ float lds[64][65];
  int lin = blockIdx.x;
  if (lin < 8192) {
    int i = (lin * 256 + threadIdx.x) * 4;
    f32x4 v = *(const f32x4*)(x + i);
    u16x4 o = {f2bf(v[0]), f2bf(v[1]), f2bf(v[2]), f2bf(v[3])};
    *(u16x4*)(xb + i) = o;
    return;
  }
  int pos = lin - 8192;
  int z = pos >> 8, rem = pos & 255;
  const float* W = z == 0 ? Wq : z == 1 ? Wk : z == 2 ? Wv : Wo;
  u16* Wt       = z == 0 ? Wqt : z == 1 ? Wkt : z == 2 ? Wvt : Wot;
  int k0 = (rem >> 4) * 64, n0 = (rem & 15) * 64;
  int tr = threadIdx.x >> 6, tc = threadIdx.x & 63;
#pragma unroll
  for (int i = 0; i < 16; ++i)
    lds[tr + i * 4][tc] = W[(size_t)(k0 + tr + i * 4) * D_ + n0 + tc];
  __syncthreads();
#pragma unroll
  for (int i = 0; i < 16; ++i)
    Wt[(size_t)(n0 + tr + i * 4) * D_ + k0 + tc] = f2bf(lds[tc][tr + i * 4]);
}

// ---------------- shared 128x128 GEMM mainloop (global_load_lds staging, XOR swizzle) ----------------
__device__ __forceinline__ void gemm_main(const u16* __restrict__ A, const u16* __restrict__ Bt,
                                          u16* As, u16* Bs, int row0, int col0, f32x4 acc[4][4]) {
  const int tid = threadIdx.x;
  const int lane = tid & 63, wave = tid >> 6;
  const int wr = wave >> 1, wc = wave & 1;
  const int l15 = lane & 15, lg = lane >> 4;
  const int sr8 = lane >> 3;        // row within this wave's 8-row chunk (= r&7)
  const int scx = (lane & 7) ^ sr8; // pre-swizzled source k-chunk
#pragma unroll 1
  for (int k0 = 0; k0 < D_; k0 += 64) {
    // issue async stages: 4 wave-chunks of 8 rows for A and B each
#pragma unroll
    for (int it = 0; it < 4; ++it) {
      int rbase = (it * 4 + wave) * 8;
      int r = rbase + sr8;
      gload_lds16(A + (size_t)(row0 + r) * D_ + k0 + scx * 8, As + rbase * 64);
      gload_lds16(Bt + (size_t)(col0 + r) * D_ + k0 + scx * 8, Bs + rbase * 64);
    }
    __syncthreads();  // drains vmcnt -> DMA writes visible; syncs waves
#pragma unroll
    for (int kk = 0; kk < 64; kk += 32) {
      const int cb = kk >> 3;  // 0 or 4
      bf16x8 af[4], bf[4];
#pragma unroll
      for (int m = 0; m < 4; ++m) {
        int row = wr * 64 + m * 16 + l15;
        af[m] = *(const bf16x8*)(As + row * 64 + (((cb + lg) ^ (l15 & 7)) << 3));
      }
#pragma unroll
      for (int n = 0; n < 4; ++n) {
        int row = wc * 64 + n * 16 + l15;
        bf[n] = *(const bf16x8*)(Bs + row * 64 + (((cb + lg) ^ (l15 & 7)) << 3));
      }
#pragma unroll
      for (int m = 0; m < 4; ++m)
#pragma unroll
        for (int n = 0; n < 4; ++n)
          acc[m][n] = __builtin_amdgcn_mfma_f32_16x16x32_bf16(af[m], bf[n], acc[m][n], 0, 0, 0);
    }
    __syncthreads();  // readers done before next iteration's DMA writes
  }
}

// ---------------- QKV projection GEMM (1D grid, XCD-clustered swizzle) ----------------
__global__ __launch_bounds__(256) void qkv_gemm_kernel(const u16* __restrict__ xb,
                                                       const u16* __restrict__ Wqt, const u16* __restrict__ Wkt,
                                                       const u16* __restrict__ Wvt,
                                                       u16* __restrict__ Qb, u16* __restrict__ Kb,
                                                       _Float16* __restrict__ Vt) {
  __shared__ u16 As[128 * 64];
  __shared__ u16 Bs[128 * 64];
  int lin = blockIdx.x;
  int xcd = lin & 7, pos = lin >> 3;      // pos in [0,192)
  int mode = pos / 64;                    // z outer
  int rem = pos & 63;
  int by = xcd * 8 + (rem >> 3);          // row-panel
  int bx = rem & 7;                       // col-tile
  const u16* Bt = mode == 0 ? Wqt : mode == 1 ? Wkt : Wvt;
  f32x4 acc[4][4] = {};
  int row0 = by * 128, col0 = bx * 128;
  gemm_main(xb, Bt, As, Bs, row0, col0, acc);
  int lane = threadIdx.x & 63, wave = threadIdx.x >> 6;
  int wr = wave >> 1, wc = wave & 1, l15 = lane & 15, lg = lane >> 4;
  int rbase = row0 + wr * 64 + lg * 4, cbase = col0 + wc * 64 + l15;
  if (mode == 2) {
#pragma unroll
    for (int m = 0; m < 4; ++m) {
      int row = rbase + m * 16;
      int b = row >> 11, s = row & (S_ - 1);
#pragma unroll
      for (int n = 0; n < 4; ++n) {
        int col = cbase + n * 16;
        int h = col >> 6, hd = col & 63;
        f16x4 vv = {(_Float16)acc[m][n][0], (_Float16)acc[m][n][1],
                    (_Float16)acc[m][n][2], (_Float16)acc[m][n][3]};
        *(f16x4*)(Vt + ((size_t)((b << 4) + h) * HD_ + hd) * S_ + s) = vv;
      }
    }
  } else {
    u16* dst = mode == 0 ? Qb : Kb;
    float scl = mode == 0 ? QSCALE : 1.0f;
#pragma unroll
    for (int m = 0; m < 4; ++m)
#pragma unroll
      for (int n = 0; n < 4; ++n) {
        int col = cbase + n * 16;
#pragma unroll
        for (int r = 0; r < 4; ++r) {
          int row = rbase + m * 16 + r;
          dst[(size_t)row * D_ + col] = f2bf(acc[m][n][r] * scl);
        }
      }
  }
}

// ---------------- fused causal flash attention, v17 (r22-exact: best measured, 86.7us) ----------------
// Block = 2 waves / 128 threads / 64 q rows; 2048 blocks (qblk x bh), LPT, XCD clustering,
// single-buffer 18KB LDS, 2-barrier tile loop with reg-staged prefetch; peeled diagonal tile.
// P->B-fragment redistribution uses v_permlane32_swap (VALU); tmax reduce keeps __shfl_xor
// (the swap(t,t) variant was proven WRONG in r23 — do not reintroduce).
__global__ __launch_bounds__(128) void attn_kernel(const u16* __restrict__ Qb, const u16* __restrict__ Kb,
                                                   const _Float16* __restrict__ Vt, u16* __restrict__ attnb) {
  __shared__ u16 Ks[64][LDP];       // [kv][hd]
  __shared__ _Float16 Vs[64][LDP];  // [hd][kv]
  const int tid = threadIdx.x;
  const int wave = tid >> 6, lane = tid & 63;
  const int l31 = lane & 31, hi = lane >> 5;
  const int lin = blockIdx.x;
  const int xcd = lin & 7, slot = lin >> 3;   // slot 0..255
  const int qblk = 31 - (slot >> 3);          // LPT: biggest first
  const int bh = (slot & 7) * 8 + xcd;        // bh&7 == xcd
  const int b = bh >> 4, h = bh & 15;
  const int ntiles = qblk + 1;
  const int wq0 = qblk * 64 + wave * 32;      // wave's rows [wq0, wq0+32)
  const int qg = wq0 + l31;                   // this lane's q row

  // staging: thread covers K/V row (tid>>1), 32-elem half (tid&1)*32
  const int srow = tid >> 1;
  const int sh = (tid & 1) * 32;
  const u16* Kp = Kb + (size_t)(b * S_ + srow) * D_ + h * HD_ + sh;
  const _Float16* Vp = Vt + ((size_t)bh * HD_ + srow) * S_ + sh;

  // Q B-fragments per 16-wide d-step
  const u16* Qrow = Qb + (size_t)(b * S_ + qg) * D_ + h * HD_;
  bf16x8 qf[4];
#pragma unroll
  for (int ds = 0; ds < 4; ++ds)
    qf[ds] = *(const bf16x8*)(Qrow + ds * 16 + hi * 8);

  float m = -1e30f;
  f32x16 oL = {}, oH = {};   // o^T rows hd 0..31 / 32..63, col q = l31
  f32x16 osum = {};          // ones-MFMA row-sum: every reg == Σ P for col q = l31
  const f16x8 ones8 = {(_Float16)1.f, (_Float16)1.f, (_Float16)1.f, (_Float16)1.f,
                       (_Float16)1.f, (_Float16)1.f, (_Float16)1.f, (_Float16)1.f};
  u32x4 kst[4], vst[4];

  // tile body (domask is compile-time constant at each inlined call site)
  auto tile_body = [&](int kvb, bool domask) {
    f32x16 sA = {}, sB = {};
    __builtin_amdgcn_s_setprio(1);
#pragma unroll
    for (int ds = 0; ds < 4; ++ds) {
      bf16x8 k0 = *(const bf16x8*)(&Ks[l31][ds * 16 + hi * 8]);
      bf16x8 k1 = *(const bf16x8*)(&Ks[32 + l31][ds * 16 + hi * 8]);
      sA = __builtin_amdgcn_mfma_f32_32x32x16_bf16(k0, qf[ds], sA, 0, 0, 0);
      sB = __builtin_amdgcn_mfma_f32_32x32x16_bf16(k1, qf[ds], sB, 0, 0, 0);
    }
    __builtin_amdgcn_s_setprio(0);
    if (domask) {
#pragma unroll
      for (int r = 0; r < 16; ++r) {
        int off = (r & 3) + 8 * (r >> 2) + 4 * hi;
        if (kvb + off > qg) sA[r] = -1e30f;
        if (kvb + 32 + off > qg) sB[r] = -1e30f;
      }
    }
    float mx[16];
#pragma unroll
    for (int r = 0; r < 16; ++r) mx[r] = fmaxf(sA[r], sB[r]);
    float y0 = max3f(mx[0], mx[1], mx[2]);
    float y1 = max3f(mx[3], mx[4], mx[5]);
    float y2 = max3f(mx[6], mx[7], mx[8]);
    float y3 = max3f(mx[9], mx[10], mx[11]);
    float y4 = max3f(mx[12], mx[13], mx[14]);
    float tmax = fmaxf(max3f(y0, y1, y2), max3f(y3, y4, mx[15]));
    tmax = fmaxf(tmax, __shfl_xor(tmax, 32));
    if (!__all(tmax - m <= 8.f)) {  // defer-max (T13)
      float nm = fmaxf(m, tmax);
      float alpha = exp2f(m - nm);
      m = nm;
      osum *= alpha;
      oL *= alpha;
      oH *= alpha;
    }
#pragma unroll
    for (int r = 0; r < 16; ++r) {
      sA[r] = exp2f(sA[r] - m);
      sB[r] = exp2f(sB[r] - m);
    }
    u32 uA[8], uB[8];
#pragma unroll
    for (int k = 0; k < 8; ++k) {
      uA[k] = __builtin_bit_cast(u32, __builtin_amdgcn_cvt_pkrtz(sA[2 * k], sA[2 * k + 1]));
      uB[k] = __builtin_bit_cast(u32, __builtin_amdgcn_cvt_pkrtz(sB[2 * k], sB[2 * k + 1]));
    }
    // permlane32_swap: out0 = {x_lo | y_lo}, out1 = {x_hi | y_hi} (lane-positioned).
    // Verified vs select logic (r22 passed): ks0.w0 = swap(u0,u2).out0, ks0.w2 = .out1, etc.
    u32 w[4][4];
    {
      auto pA0 = __builtin_amdgcn_permlane32_swap(uA[0], uA[2], false, false);
      auto pA1 = __builtin_amdgcn_permlane32_swap(uA[1], uA[3], false, false);
      w[0][0] = pA0[0]; w[0][1] = pA1[0]; w[0][2] = pA0[1]; w[0][3] = pA1[1];
      auto pA2 = __builtin_amdgcn_permlane32_swap(uA[4], uA[6], false, false);
      auto pA3 = __builtin_amdgcn_permlane32_swap(uA[5], uA[7], false, false);
      w[1][0] = pA2[0]; w[1][1] = pA3[0]; w[1][2] = pA2[1]; w[1][3] = pA3[1];
      auto pB0 = __builtin_amdgcn_permlane32_swap(uB[0], uB[2], false, false);
      auto pB1 = __builtin_amdgcn_permlane32_swap(uB[1], uB[3], false, false);
      w[2][0] = pB0[0]; w[2][1] = pB1[0]; w[2][2] = pB0[1]; w[2][3] = pB1[1];
      auto pB2 = __builtin_amdgcn_permlane32_swap(uB[4], uB[6], false, false);
      auto pB3 = __builtin_amdgcn_permlane32_swap(uB[5], uB[7], false, false);
      w[3][0] = pB2[0]; w[3][1] = pB3[0]; w[3][2] = pB2[1]; w[3][3] = pB3[1];
    }
    __builtin_amdgcn_s_setprio(1);
#pragma unroll
    for (int ks = 0; ks < 4; ++ks) {
      f16x8 pa = __builtin_bit_cast(f16x8, (u32x4){w[ks][0], w[ks][1], w[ks][2], w[ks][3]});
      f16x8 v0 = *(const f16x8*)(&Vs[l31][ks * 16 + hi * 8]);
      f16x8 v1 = *(const f16x8*)(&Vs[32 + l31][ks * 16 + hi * 8]);
      oL = __builtin_amdgcn_mfma_f32_32x32x16_f16(v0, pa, oL, 0, 0, 0);
      oH = __builtin_amdgcn_mfma_f32_32x32x16_f16(v1, pa, oH, 0, 0, 0);
      osum = __builtin_amdgcn_mfma_f32_32x32x16_f16(ones8, pa, osum, 0, 0, 0);
    }
    __builtin_amdgcn_s_setprio(0);
  };

  // prologue: tile 0 -> regs
#pragma unroll
  for (int c = 0; c < 4; ++c) {
    kst[c] = *(const u32x4*)(Kp + c * 8);
    vst[c] = *(const u32x4*)(Vp + c * 8);
  }
  Kp += (size_t)64 * D_;
  Vp += 64;

  // main loop: tiles 0 .. ntiles-2 (no mask, unconditional prefetch)
#pragma unroll 1
  for (int t = 0; t < ntiles - 1; ++t) {
    __syncthreads();  // previous tile's readers done
#pragma unroll
    for (int c = 0; c < 4; ++c) {
      *(u32x4*)(&Ks[srow][sh + c * 8]) = kst[c];
      *(u32x4*)(&Vs[srow][sh + c * 8]) = vst[c];
    }
    __syncthreads();  // writes visible
#pragma unroll
    for (int c = 0; c < 4; ++c) {
      kst[c] = *(const u32x4*)(Kp + c * 8);
      vst[c] = *(const u32x4*)(Vp + c * 8);
    }
    Kp += (size_t)64 * D_;
    Vp += 64;
    tile_body(t * 64, false);
  }

  // peeled final (diagonal) tile
  __syncthreads();
#pragma unroll
  for (int c = 0; c < 4; ++c) {
    *(u32x4*)(&Ks[srow][sh + c * 8]) = kst[c];
    *(u32x4*)(&Vs[srow][sh + c * 8]) = vst[c];
  }
  __syncthreads();
  tile_body((ntiles - 1) * 64, true);

  // ---- epilogue: normalize (osum spans both halves -> lane-local), transpose via K-LDS ----
  float inv = 1.0f / osum[0];
  __syncthreads();  // both waves done reading Ks/Vs
  u16* scr = &Ks[wave * 32 + l31][0];  // scratch row = this lane's q
#pragma unroll
  for (int a = 0; a < 4; ++a) {
    u16x4 pl = {f2bf(oL[4 * a + 0] * inv), f2bf(oL[4 * a + 1] * inv),
                f2bf(oL[4 * a + 2] * inv), f2bf(oL[4 * a + 3] * inv)};
    *(u16x4*)(scr + 8 * a + 4 * hi) = pl;
    u16x4 ph = {f2bf(oH[4 * a + 0] * inv), f2bf(oH[4 * a + 1] * inv),
                f2bf(oH[4 * a + 2] * inv), f2bf(oH[4 * a + 3] * inv)};
    *(u16x4*)(scr + 32 + 8 * a + 4 * hi) = ph;
  }
  asm volatile("s_waitcnt lgkmcnt(0)" ::: "memory");
  const u16* srd = &Ks[wave * 32 + l31][hi * 32];
  u16* Og = attnb + (size_t)(b * S_ + wq0 + l31) * D_ + h * HD_ + hi * 32;
#pragma unroll
  for (int c = 0; c < 4; ++c)
    *(u32x4*)(Og + c * 8) = *(const u32x4*)(srd + c * 8);
}

// ---------------- output projection GEMM (fp32 out + bias, XCD-clustered swizzle) ----------------
__global__ __launch_bounds__(256) void out_gemm_kernel(const u16* __restrict__ attnb, const u16* __restrict__ Wot,
                                                       const float* __restrict__ bo, float* __restrict__ outp) {
  __shared__ u16 As[128 * 64];
  __shared__ u16 Bs[128 * 64];
  int lin = blockIdx.x;
  int xcd = lin & 7, pos = lin >> 3;  // pos in [0,64)
  int by = xcd * 8 + (pos >> 3);
  int bx = pos & 7;
  f32x4 acc[4][4] = {};
  int row0 = by * 128, col0 = bx * 128;
  gemm_main(attnb, Wot, As, Bs, row0, col0, acc);
  int lane = threadIdx.x & 63, wave = threadIdx.x >> 6;
  int wr = wave >> 1, wc = wave & 1, l15 = lane & 15, lg = lane >> 4;
  int rbase = row0 + wr * 64 + lg * 4, cbase = col0 + wc * 64 + l15;
#pragma unroll
  for (int n = 0; n < 4; ++n) {
    float bn = bo[cbase + n * 16];
#pragma unroll
    for (int m = 0; m < 4; ++m)
#pragma unroll
      for (int r = 0; r < 4; ++r)
        outp[(size_t)(rbase + m * 16 + r) * D_ + cbase + n * 16] = acc[m][n][r] + bn;
  }
}

extern "C" void kernel_launch(void* const* d_in, const int* in_sizes, int n_in,
                              void* d_out, int out_size, void* d_ws, size_t ws_size,
                              hipStream_t stream) {
  const float* x  = (const float*)d_in[0];
  const float* Wq = (const float*)d_in[1];
  const float* Wk = (const float*)d_in[2];
  const float* Wv = (const float*)d_in[3];
  const float* Wo = (const float*)d_in[4];
  const float* bo = (const float*)d_in[5];
  float* outp = (float*)d_out;

  char* ws = (char*)d_ws;
  u16* xb        = (u16*)(ws);                          // 16 MiB
  u16* Wqt       = (u16*)(ws + ((size_t)16 << 20));     // 2 MiB
  u16* Wkt       = (u16*)(ws + ((size_t)18 << 20));
  u16* Wvt       = (u16*)(ws + ((size_t)20 << 20));
  u16* Wot       = (u16*)(ws + ((size_t)22 << 20));
  u16* Qb        = (u16*)(ws + ((size_t)24 << 20));     // 16 MiB
  u16* Kb        = (u16*)(ws + ((size_t)40 << 20));     // 16 MiB
  _Float16* Vt   = (_Float16*)(ws + ((size_t)56 << 20));// 16 MiB
  u16* attnb     = (u16*)(ws + ((size_t)72 << 20));     // 16 MiB

  prep_kernel<<<dim3(9216), dim3(256), 0, stream>>>(x, xb, Wq, Wk, Wv, Wo, Wqt, Wkt, Wvt, Wot);
  qkv_gemm_kernel<<<dim3(1536), dim3(256), 0, stream>>>(xb, Wqt, Wkt, Wvt, Qb, Kb, Vt);
  attn_kernel<<<dim3(2048), dim3(128), 0, stream>>>(Qb, Kb, Vt, attnb);
  out_gemm_kernel<<<dim3(512), dim3(256), 0, stream>>>(attnb, Wot, bo, outp);
}